// Round 4
// baseline (3450.940 us; speedup 1.0000x reference)
//
#include <hip/hip_runtime.h>

// Kalman filter, B=256 T=512 S=64 M=32.
// Kernel 1 (1 WG, 1024 thr): batch-independent Riccati recursion with
// CONVERGED Newton-Schulz inverse (residual-checked, rescue re-init) — the
// round-2-proven structure. Runs exactly T_EXACT steps (deterministic freeze:
// gain drift beyond t=192 is ~1e-8 since dP ~ rho(A)^{2t}, rho<=0.955), then
// emits closed-loop A = F(I-KH), G = FK. Writes K^T[t] ([64][32]) per step.
// Kernel 2 (256 blocks x 1 wave, one block per batch): linear state recursion.
// t < T_EXACT: exact K_t (coalesced 128B/lane rows) + f4 LDS broadcasts.
// t >= T_EXACT: x <- A x + G o with A,G,H rows in VGPRs.

#define Sdim 64
#define Mdim 32
#define Tdim 512
#define T_EXACT 192

#define NEWTON_TOL 1.5e-4f

typedef float f4 __attribute__((ext_vector_type(4)));

// ---------------------------------------------------------------------------
// Kernel 1: Riccati recursion (single workgroup, 1024 threads)
// ---------------------------------------------------------------------------
__global__ __launch_bounds__(1024)
void riccati_kernel(const float* __restrict__ F, const float* __restrict__ H,
                    const float* __restrict__ Q, const float* __restrict__ R,
                    const float* __restrict__ P0,
                    float* __restrict__ K_T,      // [T_EXACT][64][32] f32
                    float* __restrict__ AT_g,     // [16][64] f4 (A[l][4j..] at [j][l])
                    float* __restrict__ GT_g)     // [8][64]  f4
{
    __shared__ __align__(16) float Ps [64*64];
    __shared__ __align__(16) float Gs [64*68];     // stride-68 scratch (also FK @33)
    __shared__ __align__(16) float HPs[32*64];
    __shared__ __align__(16) float Hs [32*65+4];
    __shared__ __align__(16) float Fs [64*65+4];
    __shared__ __align__(16) float FTs[64*64];
    __shared__ __align__(16) float Sms[32*33+4];
    __shared__ __align__(16) float Ys [32*33+4];
    __shared__ __align__(16) float T1s[32*33+4];
    __shared__ __align__(16) float Yns[32*33+4];
    __shared__ __align__(16) float KpT[64*33+4];   // K'^T: KpT[s*33+m] = K'[m][s]
    __shared__ int red_a, restarted;

    const int tid = threadIdx.x;
    f4* Ps4  = (f4*)Ps;
    f4* Gs4  = (f4*)Gs;
    f4* HP4  = (f4*)HPs;
    f4* FT4  = (f4*)FTs;
    f4* KT_g4 = (f4*)K_T;
    f4* AT_g4 = (f4*)AT_g;
    f4* GT_g4 = (f4*)GT_g;
    const f4* Q4 = (const f4*)Q;

    for (int i = tid; i < 64*64; i += 1024) {
        int r = i >> 6, c = i & 63;
        float v = F[i];
        Fs[r*65 + c] = v;
        FTs[c*64 + r] = v;      // FT[k][l] = F[l][k]
        Ps[i] = P0[i];
    }
    for (int i = tid; i < 32*64; i += 1024) {
        int mm = i >> 6, c = i & 63;
        Hs[mm*65 + c] = H[i];
    }
    __syncthreads();

    const int r16 = tid >> 4, j16 = tid & 15;   // [64 rows x 16 f4-cols]
    const int i32 = tid >> 5, j32 = tid & 31;   // [32 x 32]

    { // initial predict: Ps = F P0 F^T + Q
        f4 acc = {0.f,0.f,0.f,0.f};
        #pragma unroll 8
        for (int k = 0; k < 64; ++k) acc += Fs[r16*65 + k] * Ps4[k*16 + j16];
        Gs4[r16*17 + j16] = acc;
    }
    __syncthreads();
    {
        f4 acc = Q4[r16*16 + j16];
        #pragma unroll 8
        for (int k = 0; k < 64; ++k) acc += Gs[r16*68 + k] * FT4[k*16 + j16];
        Ps4[r16*16 + j16] = acc;
    }
    __syncthreads();

    float* Ycur = Ys;
    float* Yalt = Yns;

    for (int t = 0; t < T_EXACT; ++t) {
        if (tid < 512) {                        // a: HP = H * P
            int mm = tid >> 4, j = tid & 15;
            f4 acc = {0.f,0.f,0.f,0.f};
            #pragma unroll 8
            for (int k = 0; k < 64; ++k) acc += Hs[mm*65 + k] * Ps4[k*16 + j];
            HP4[mm*16 + j] = acc;
        }
        __syncthreads();
        {                                       // b: Sm = HP H^T + R
            float acc = R[i32*32 + j32];
            #pragma unroll 8
            for (int s = 0; s < 64; ++s) acc += HPs[i32*64 + s] * Hs[j32*65 + s];
            Sms[i32*33 + j32] = acc;
            if (tid == 0) { red_a = 0; restarted = 0; }
        }
        __syncthreads();

        if (t == 0) {                           // Newton init: Y = I / maxrowsum
            if (tid < 32) {
                float rs = 0.f;
                for (int jj = 0; jj < 32; ++jj) rs += fabsf(Sms[tid*33 + jj]);
                atomicMax(&red_a, __float_as_int(rs));
            }
            __syncthreads();
            float inv = 1.0f / __int_as_float(red_a);
            Ycur[i32*33 + j32] = (i32 == j32) ? inv : 0.f;
            if (tid == 0) red_a = 0;
            __syncthreads();
        }

        // --- Newton-Schulz: converge Y ~= Sm^{-1} (check-first + rescue)
        for (int it = 0; it < 40; ++it) {
            float acc = 0.f;
            #pragma unroll 8
            for (int k = 0; k < 32; ++k) acc += Sms[i32*33 + k] * Ycur[k*33 + j32];
            T1s[i32*33 + j32] = acc;
            float e = fabsf(((i32 == j32) ? 1.f : 0.f) - acc);
            atomicMax(&red_a, __float_as_int(e));
            __syncthreads();
            float resid = __int_as_float(red_a);        // uniform
            if (resid < NEWTON_TOL) break;
            bool bad = !(resid < 1e30f);
            if ((bad || (it >= 12 && resid > 0.9f)) && restarted == 0) {
                if (tid == 0) red_a = 0;
                __syncthreads();
                if (tid < 32) {
                    float rs = 0.f;
                    for (int jj = 0; jj < 32; ++jj) rs += fabsf(Sms[tid*33 + jj]);
                    atomicMax(&red_a, __float_as_int(rs));
                }
                __syncthreads();
                float inv = 1.0f / __int_as_float(red_a);
                Ycur[i32*33 + j32] = (i32 == j32) ? inv : 0.f;
                if (tid == 0) { restarted = 1; red_a = 0; }
                __syncthreads();
                continue;
            }
            float up = 2.f * Ycur[i32*33 + j32];
            #pragma unroll 8
            for (int k = 0; k < 32; ++k) up -= Ycur[i32*33 + k] * T1s[k*33 + j32];
            Yalt[i32*33 + j32] = up;
            if (tid == 0) red_a = 0;
            __syncthreads();
            float* tmp = Ycur; Ycur = Yalt; Yalt = tmp;
        }

        if (tid < 512) {                        // d: K' = Y * HP -> KpT
            int mm = tid >> 4, j = tid & 15;
            f4 acc = {0.f,0.f,0.f,0.f};
            #pragma unroll 8
            for (int n = 0; n < 32; ++n) acc += Ycur[mm*33 + n] * HP4[n*16 + j];
            int s0 = j * 4;
            KpT[(s0    )*33 + mm] = acc[0];
            KpT[(s0 + 1)*33 + mm] = acc[1];
            KpT[(s0 + 2)*33 + mm] = acc[2];
            KpT[(s0 + 3)*33 + mm] = acc[3];
        }
        __syncthreads();

        if (tid < 512) {                        // store K^T[t] coalesced (f4)
            int s = tid >> 3, m4 = tid & 7;
            f4 v = { KpT[s*33 + m4*4 + 0], KpT[s*33 + m4*4 + 1],
                     KpT[s*33 + m4*4 + 2], KpT[s*33 + m4*4 + 3] };
            KT_g4[(size_t)t*512 + tid] = v;
        }

        if (t == T_EXACT - 1) {                 // emit closed-loop A, G
            // FK[l][m] = sum_s F[l][s] K'[m][s] -> Gs stride 33
            for (int i = tid; i < 64*32; i += 1024) {
                int l = i >> 5, mm = i & 31;
                float acc = 0.f;
                #pragma unroll 8
                for (int s = 0; s < 64; ++s) acc += Fs[l*65 + s] * KpT[s*33 + mm];
                Gs[l*33 + mm] = acc;
            }
            __syncthreads();
            {   // A = F - FK*H; AT_g4[j4*64 + l] = {A[l][4j4+c]}
                int l = tid & 63, j4 = tid >> 6;
                f4 aa;
                #pragma unroll
                for (int c = 0; c < 4; ++c) {
                    int j = j4*4 + c;
                    float a = Fs[l*65 + j];
                    #pragma unroll 8
                    for (int mm = 0; mm < 32; ++mm) a -= Gs[l*33 + mm] * Hs[mm*65 + j];
                    aa[c] = a;
                }
                AT_g4[j4*64 + l] = aa;
            }
            if (tid < 512) {                    // G = FK; GT_g4[m4*64 + l]
                int l = tid & 63, m4 = tid >> 6;
                f4 gg = { Gs[l*33 + m4*4 + 0], Gs[l*33 + m4*4 + 1],
                          Gs[l*33 + m4*4 + 2], Gs[l*33 + m4*4 + 3] };
                GT_g4[m4*64 + l] = gg;
            }
            break;
        }

        {                                       // e: P -= K'^T * HP (own element)
            f4 acc = Ps4[r16*16 + j16];
            #pragma unroll 8
            for (int mm = 0; mm < 32; ++mm) acc -= KpT[r16*33 + mm] * HP4[mm*16 + j16];
            Ps4[r16*16 + j16] = acc;
        }
        __syncthreads();
        {                                       // f: G = F * P_upd
            f4 acc = {0.f,0.f,0.f,0.f};
            #pragma unroll 8
            for (int k = 0; k < 64; ++k) acc += Fs[r16*65 + k] * Ps4[k*16 + j16];
            Gs4[r16*17 + j16] = acc;
        }
        __syncthreads();
        {                                       // g: P = G F^T + Q
            f4 acc = Q4[r16*16 + j16];
            #pragma unroll 8
            for (int k = 0; k < 64; ++k) acc += Gs[r16*68 + k] * FT4[k*16 + j16];
            Ps4[r16*16 + j16] = acc;
        }
        __syncthreads();
    }
}

// ---------------------------------------------------------------------------
// Kernel 2: per-batch state recursion, one wave per batch (256 blocks x 64)
// ---------------------------------------------------------------------------
__global__ __launch_bounds__(64)
void filter_kernel(const float* __restrict__ obs, const float* __restrict__ F,
                   const float* __restrict__ H, const float* __restrict__ x0,
                   const float* __restrict__ K_T, const float* __restrict__ AT_g,
                   const float* __restrict__ GT_g, float* __restrict__ out)
{
    const int lane = threadIdx.x;
    const int b    = blockIdx.x;
    const int m    = lane & 31;

    __shared__ __align__(16) float xb[64];
    __shared__ __align__(16) float rb[32];
    __shared__ __align__(16) float ub[64];
    const f4* xb4 = (const f4*)xb;
    const f4* rb4 = (const f4*)rb;
    const f4* ub4 = (const f4*)ub;

    f4 Fr4[16], Hr4[16];
    #pragma unroll
    for (int k = 0; k < 16; ++k) Fr4[k] = ((const f4*)(F + lane*64))[k];
    #pragma unroll
    for (int k = 0; k < 16; ++k) Hr4[k] = ((const f4*)(H + m*64))[k];

    float x;
    {   // x = F x0 (initial predict)
        f4 a = {0.f,0.f,0.f,0.f};
        #pragma unroll
        for (int k = 0; k < 16; ++k) a += Fr4[k] * ((const f4*)x0)[k];
        x = (a[0]+a[1]) + (a[2]+a[3]);
    }

    const float* obs_b = obs + (size_t)b * (Tdim*Mdim);
    float*       out_b = out + (size_t)b * (Tdim*Mdim);
    float o0 = obs_b[m];
    float o1 = obs_b[Mdim + m];

    const f4* KT4 = (const f4*)K_T;

    // ---- exact phase: t in [0, T_EXACT)
    for (int t = 0; t < T_EXACT; ++t) {
        f4 ku[8];                               // lane's K^T row (128B coalesced)
        #pragma unroll
        for (int k = 0; k < 8; ++k) ku[k] = KT4[(size_t)t*512 + lane*8 + k];

        xb[lane] = x;
        asm volatile("s_waitcnt lgkmcnt(0)" ::: "memory");
        f4 za = {0.f,0.f,0.f,0.f};
        #pragma unroll
        for (int k = 0; k < 16; ++k) za += Hr4[k] * xb4[k];
        float z = (za[0]+za[1]) + (za[2]+za[3]);
        if (lane < 32) { out_b[t*Mdim + lane] = z; rb[lane] = o0 - z; }
        o0 = o1;
        if (t + 2 < Tdim) o1 = obs_b[(t+2)*Mdim + m];
        asm volatile("s_waitcnt lgkmcnt(0)" ::: "memory");
        f4 ua = {0.f,0.f,0.f,0.f};
        #pragma unroll
        for (int k = 0; k < 8; ++k) ua += ku[k] * rb4[k];
        float u = x + (ua[0]+ua[1]) + (ua[2]+ua[3]);
        ub[lane] = u;
        asm volatile("s_waitcnt lgkmcnt(0)" ::: "memory");
        f4 xa = {0.f,0.f,0.f,0.f};
        #pragma unroll
        for (int k = 0; k < 16; ++k) xa += Fr4[k] * ub4[k];
        x = (xa[0]+xa[1]) + (xa[2]+xa[3]);
    }

    // ---- frozen phase: x <- A x + G o, A/G rows in VGPRs
    {
        f4 Ar[16], Gr[8];
        #pragma unroll
        for (int k = 0; k < 16; ++k) Ar[k] = ((const f4*)AT_g)[k*64 + lane];
        #pragma unroll
        for (int k = 0; k < 8; ++k)  Gr[k] = ((const f4*)GT_g)[k*64 + lane];

        for (int t = T_EXACT; t < Tdim; ++t) {
            xb[lane] = x;
            if (lane < 32) rb[lane] = o0;
            asm volatile("s_waitcnt lgkmcnt(0)" ::: "memory");
            f4 za = {0.f,0.f,0.f,0.f}, xa = {0.f,0.f,0.f,0.f};
            #pragma unroll
            for (int k = 0; k < 16; ++k) {
                f4 xv = xb4[k];
                za += Hr4[k] * xv;
                xa += Ar[k] * xv;
            }
            #pragma unroll
            for (int k = 0; k < 8; ++k) xa += Gr[k] * rb4[k];
            float z = (za[0]+za[1]) + (za[2]+za[3]);
            if (lane < 32) out_b[t*Mdim + lane] = z;
            o0 = o1;
            if (t + 2 < Tdim) o1 = obs_b[(t+2)*Mdim + m];
            x = (xa[0]+xa[1]) + (xa[2]+xa[3]);
        }
    }
}

// ---------------------------------------------------------------------------
extern "C" void kernel_launch(void* const* d_in, const int* in_sizes, int n_in,
                              void* d_out, int out_size, void* d_ws, size_t ws_size,
                              hipStream_t stream)
{
    const float* obs = (const float*)d_in[0];
    const float* F   = (const float*)d_in[1];
    const float* H   = (const float*)d_in[2];
    const float* Q   = (const float*)d_in[3];
    const float* R   = (const float*)d_in[4];
    const float* x0  = (const float*)d_in[5];
    const float* P0  = (const float*)d_in[6];
    float* out = (float*)d_out;

    // ws: K_T (192*64*32 f32 = 1.5 MiB) | AT (16 KB) @ +2 MiB | GT (8 KB)
    float* K_T  = (float*)d_ws;
    float* AT_g = (float*)((char*)d_ws + (2u << 20));
    float* GT_g = (float*)((char*)d_ws + (2u << 20) + 64*64*sizeof(float));

    hipLaunchKernelGGL(riccati_kernel, dim3(1), dim3(1024), 0, stream,
                       F, H, Q, R, P0, K_T, AT_g, GT_g);
    hipLaunchKernelGGL(filter_kernel, dim3(256), dim3(64), 0, stream,
                       obs, F, H, x0, K_T, AT_g, GT_g, out);
}